// Round 1
// baseline (90.815 us; speedup 1.0000x reference)
//
#include <hip/hip_runtime.h>
#include <cmath>

#define IMG_H 512
#define IMG_W 512
#define TILE_X 64
#define TILE_Y 32
#define LH 42          // TILE_Y + 10 halo rows
#define LW 74          // TILE_X + 10 halo cols (stored with stride 76 for float4 alignment)
#define LSTRIDE 76
#define NBLOCKS (8 * 16 * 32)
#define NPIX (8 * 4 * 512 * 512)

struct Weights { float w[11]; };

__global__ __launch_bounds__(256, 2)
void ssim_tile_kernel(const float* __restrict__ pred,
                      const float* __restrict__ targ,
                      float* __restrict__ partials,
                      Weights wt)
{
    __shared__ float sp[LH * LSTRIDE];   // pred tile   (42x76)  12.8KB
    __shared__ float st[LH * LSTRIDE];   // target tile          12.8KB
    __shared__ float h1[LH * TILE_X];    // horizontal conv of p       10.5KB
    __shared__ float h2[LH * TILE_X];    // ... of t
    __shared__ float h11[LH * TILE_X];   // ... of p*p
    __shared__ float h22[LH * TILE_X];   // ... of t*t
    __shared__ float h12[LH * TILE_X];   // ... of p*t
    __shared__ float wsum[4];

    const int tid = threadIdx.x;
    const int x0 = blockIdx.x * TILE_X;
    const int y0 = blockIdx.y * TILE_Y;
    const int plane = blockIdx.z;
    const float* __restrict__ P = pred + (size_t)plane * IMG_H * IMG_W;
    const float* __restrict__ T = targ + (size_t)plane * IMG_H * IMG_W;

    // ---- Phase A: load input tile (with zero padding outside image) ----
    for (int i = tid; i < LH * LW; i += 256) {
        int r = i / LW;
        int c = i - r * LW;
        int gy = y0 + r - 5;
        int gx = x0 + c - 5;
        float p = 0.f, t = 0.f;
        if (((unsigned)gy < IMG_H) & ((unsigned)gx < IMG_W)) {
            p = P[gy * IMG_W + gx];
            t = T[gy * IMG_W + gx];
        }
        sp[r * LSTRIDE + c] = p;
        st[r * LSTRIDE + c] = t;
    }
    __syncthreads();

    // ---- Phase B: horizontal 11-tap pass, 4 outputs per work item (float4 LDS I/O) ----
    // work items: 42 rows x 16 col-groups (4 cols each) = 672
    for (int i = tid; i < LH * 16; i += 256) {
        int r = i >> 4;
        int c4 = (i & 15) * 4;
        const float* rp = sp + r * LSTRIDE + c4;   // 16B aligned (76 and c4 both %4==0)
        const float* rt = st + r * LSTRIDE + c4;
        float p[16], t[16];
        #pragma unroll
        for (int q = 0; q < 4; ++q) {
            *(float4*)&p[q * 4] = *(const float4*)&rp[q * 4];
            *(float4*)&t[q * 4] = *(const float4*)&rt[q * 4];
        }
        float s1[4], s2[4], s11[4], s22[4], s12[4];
        #pragma unroll
        for (int o = 0; o < 4; ++o) { s1[o]=0.f; s2[o]=0.f; s11[o]=0.f; s22[o]=0.f; s12[o]=0.f; }
        #pragma unroll
        for (int k = 0; k < 11; ++k) {
            float w = wt.w[k];
            #pragma unroll
            for (int o = 0; o < 4; ++o) {
                float pv = p[o + k], tv = t[o + k];
                float wp = w * pv, wtv = w * tv;
                s1[o]  += wp;
                s2[o]  += wtv;
                s11[o] += wp * pv;
                s22[o] += wtv * tv;
                s12[o] += wp * tv;
            }
        }
        int ho = r * TILE_X + c4;
        *(float4*)&h1[ho]  = make_float4(s1[0],  s1[1],  s1[2],  s1[3]);
        *(float4*)&h2[ho]  = make_float4(s2[0],  s2[1],  s2[2],  s2[3]);
        *(float4*)&h11[ho] = make_float4(s11[0], s11[1], s11[2], s11[3]);
        *(float4*)&h22[ho] = make_float4(s22[0], s22[1], s22[2], s22[3]);
        *(float4*)&h12[ho] = make_float4(s12[0], s12[1], s12[2], s12[3]);
    }
    __syncthreads();

    // ---- Phase C: vertical 11-tap pass + SSIM, 8 output rows per thread ----
    const int c  = tid & 63;          // output column
    const int r0 = (tid >> 6) * 8;    // first output row of this thread
    float a1[8], a2[8], a11[8], a22[8], a12[8];
    #pragma unroll
    for (int o = 0; o < 8; ++o) { a1[o]=0.f; a2[o]=0.f; a11[o]=0.f; a22[o]=0.f; a12[o]=0.f; }

    #pragma unroll
    for (int j = 0; j < 18; ++j) {     // h rows r0 .. r0+17 cover outputs r0..r0+7
        int hr = (r0 + j) * TILE_X + c;
        float v1  = h1[hr];
        float v2  = h2[hr];
        float v11 = h11[hr];
        float v22 = h22[hr];
        float v12 = h12[hr];
        #pragma unroll
        for (int o = 0; o < 8; ++o) {
            int k = j - o;
            if (k >= 0 && k < 11) {
                float w = wt.w[k];
                a1[o]  += w * v1;
                a2[o]  += w * v2;
                a11[o] += w * v11;
                a22[o] += w * v22;
                a12[o] += w * v12;
            }
        }
    }

    float lsum = 0.f;
    #pragma unroll
    for (int o = 0; o < 8; ++o) {
        float mu1 = a1[o], mu2 = a2[o];
        float m11 = mu1 * mu1, m22 = mu2 * mu2, m12 = mu1 * mu2;
        float sg1 = a11[o] - m11;
        float sg2 = a22[o] - m22;
        float sg12 = a12[o] - m12;
        float num = (2.f * m12 + 1e-4f) * (2.f * sg12 + 9e-4f);
        float den = (m11 + m22 + 1e-4f) * (sg1 + sg2 + 9e-4f);
        lsum += num / den;
    }

    // ---- Block reduction (deterministic): wave shfl + LDS across 4 waves ----
    #pragma unroll
    for (int off = 32; off > 0; off >>= 1) lsum += __shfl_down(lsum, off);
    if ((tid & 63) == 0) wsum[tid >> 6] = lsum;
    __syncthreads();
    if (tid == 0) {
        float bsum = wsum[0] + wsum[1] + wsum[2] + wsum[3];
        partials[(blockIdx.z * gridDim.y + blockIdx.y) * gridDim.x + blockIdx.x] = bsum;
    }
}

__global__ void ssim_finalize(const float* __restrict__ partials, float* __restrict__ out)
{
    __shared__ double red[256];
    double s = 0.0;
    for (int i = threadIdx.x; i < NBLOCKS; i += 256) s += (double)partials[i];
    red[threadIdx.x] = s;
    __syncthreads();
    for (int stride = 128; stride > 0; stride >>= 1) {
        if ((int)threadIdx.x < stride) red[threadIdx.x] += red[threadIdx.x + stride];
        __syncthreads();
    }
    if (threadIdx.x == 0) out[0] = (float)(1.0 - red[0] / (double)NPIX);
}

extern "C" void kernel_launch(void* const* d_in, const int* in_sizes, int n_in,
                              void* d_out, int out_size, void* d_ws, size_t ws_size,
                              hipStream_t stream) {
    const float* pred = (const float*)d_in[0];
    const float* targ = (const float*)d_in[1];
    float* out = (float*)d_out;
    float* partials = (float*)d_ws;   // 4096 floats = 16KB, every slot written each call

    Weights wt;
    {
        float g[11];
        float s = 0.f;
        for (int i = 0; i < 11; ++i) {
            float d = (float)(i - 5);
            g[i] = expf(-d * d / (2.f * 1.5f * 1.5f));
            s += g[i];
        }
        for (int i = 0; i < 11; ++i) wt.w[i] = g[i] / s;
    }

    dim3 grid(IMG_W / TILE_X, IMG_H / TILE_Y, 32);   // (8, 16, 32) = 4096 blocks
    ssim_tile_kernel<<<grid, 256, 0, stream>>>(pred, targ, partials, wt);
    ssim_finalize<<<1, 256, 0, stream>>>(partials, out);
}

// Round 2
// 73.131 us; speedup vs baseline: 1.2418x; 1.2418x over previous
//
#include <hip/hip_runtime.h>
#include <cmath>

#define IMG_H 512
#define IMG_W 512
#define TILE_X 64
#define TILE_Y 32
#define LH 42          // TILE_Y + 10 halo rows of horizontal-conv output
#define NBLOCKS (8 * 16 * 32)
#define NPIX (8 * 4 * 512 * 512)

struct Weights { float w[11]; };

// 512 threads = 8 waves/block; LDS 53.8KB -> 2 blocks/CU -> 16 waves/CU (50% occ)
__global__ __launch_bounds__(512, 4)
void ssim_tile_kernel(const float* __restrict__ pred,
                      const float* __restrict__ targ,
                      float* __restrict__ partials,
                      Weights wt)
{
    __shared__ float h1[LH * TILE_X];    // horizontal conv of p    10.5KB
    __shared__ float h2[LH * TILE_X];    // ... of t
    __shared__ float h11[LH * TILE_X];   // ... of p*p
    __shared__ float h22[LH * TILE_X];   // ... of t*t
    __shared__ float h12[LH * TILE_X];   // ... of p*t
    __shared__ float wsum[8];

    const int tid = threadIdx.x;
    const int x0 = blockIdx.x * TILE_X;
    const int y0 = blockIdx.y * TILE_Y;
    const int plane = blockIdx.z;
    const float* __restrict__ P = pred + (size_t)plane * IMG_H * IMG_W;
    const float* __restrict__ T = targ + (size_t)plane * IMG_H * IMG_W;

    // ---- Phase B: horizontal 11-tap pass directly from global memory ----
    // work items: 42 rows x 16 col-groups (4 outputs each) = 672
    // Each item loads 5 aligned float4 per input covering [c4-8, c4+12);
    // window for outputs o=0..3 is p[o+3 .. o+13]. Overlap between adjacent
    // lanes is absorbed by L1/L2 (coalesced shifted dwordx4 streams).
    for (int i = tid; i < LH * 16; i += 512) {
        int r = i >> 4;
        int c4 = (i & 15) * 4;
        int gy = y0 + r - 5;
        float p[20], t[20];
        if ((unsigned)gy < IMG_H) {
            const float* rp = P + gy * IMG_W;
            const float* rt = T + gy * IMG_W;
            int gx0 = x0 + c4 - 8;                 // 16B aligned
            if (gx0 >= 0 && gx0 + 20 <= IMG_W) {   // fast path (interior in x)
                #pragma unroll
                for (int q = 0; q < 5; ++q) {
                    *(float4*)&p[q * 4] = *(const float4*)&rp[gx0 + q * 4];
                    *(float4*)&t[q * 4] = *(const float4*)&rt[gx0 + q * 4];
                }
            } else {                               // image x-edge: guarded scalar
                #pragma unroll
                for (int q = 0; q < 20; ++q) {
                    int gx = gx0 + q;
                    bool v = (unsigned)gx < IMG_W;
                    p[q] = v ? rp[gx] : 0.f;
                    t[q] = v ? rt[gx] : 0.f;
                }
            }
        } else {
            #pragma unroll
            for (int q = 0; q < 20; ++q) { p[q] = 0.f; t[q] = 0.f; }
        }

        float s1[4], s2[4], s11[4], s22[4], s12[4];
        #pragma unroll
        for (int o = 0; o < 4; ++o) { s1[o]=0.f; s2[o]=0.f; s11[o]=0.f; s22[o]=0.f; s12[o]=0.f; }
        #pragma unroll
        for (int k = 0; k < 11; ++k) {
            float w = wt.w[k];
            #pragma unroll
            for (int o = 0; o < 4; ++o) {
                float pv = p[o + 3 + k], tv = t[o + 3 + k];
                float wp = w * pv, wtv = w * tv;
                s1[o]  += wp;
                s2[o]  += wtv;
                s11[o] += wp * pv;
                s22[o] += wtv * tv;
                s12[o] += wp * tv;
            }
        }
        int ho = r * TILE_X + c4;
        *(float4*)&h1[ho]  = make_float4(s1[0],  s1[1],  s1[2],  s1[3]);
        *(float4*)&h2[ho]  = make_float4(s2[0],  s2[1],  s2[2],  s2[3]);
        *(float4*)&h11[ho] = make_float4(s11[0], s11[1], s11[2], s11[3]);
        *(float4*)&h22[ho] = make_float4(s22[0], s22[1], s22[2], s22[3]);
        *(float4*)&h12[ho] = make_float4(s12[0], s12[1], s12[2], s12[3]);
    }
    __syncthreads();

    // ---- Phase C: vertical 11-tap pass + SSIM, 4 output rows per thread ----
    const int c  = tid & 63;          // output column (contiguous -> conflict-free)
    const int r0 = (tid >> 6) * 4;    // first output row of this thread (8 groups)
    float a1[4], a2[4], a11[4], a22[4], a12[4];
    #pragma unroll
    for (int o = 0; o < 4; ++o) { a1[o]=0.f; a2[o]=0.f; a11[o]=0.f; a22[o]=0.f; a12[o]=0.f; }

    #pragma unroll
    for (int j = 0; j < 14; ++j) {     // h rows r0 .. r0+13 cover outputs r0..r0+3
        int hr = (r0 + j) * TILE_X + c;
        float v1  = h1[hr];
        float v2  = h2[hr];
        float v11 = h11[hr];
        float v22 = h22[hr];
        float v12 = h12[hr];
        #pragma unroll
        for (int o = 0; o < 4; ++o) {
            int k = j - o;
            if (k >= 0 && k < 11) {    // compile-time resolved (j,o unrolled)
                float w = wt.w[k];
                a1[o]  += w * v1;
                a2[o]  += w * v2;
                a11[o] += w * v11;
                a22[o] += w * v22;
                a12[o] += w * v12;
            }
        }
    }

    float lsum = 0.f;
    #pragma unroll
    for (int o = 0; o < 4; ++o) {
        float mu1 = a1[o], mu2 = a2[o];
        float m11 = mu1 * mu1, m22 = mu2 * mu2, m12 = mu1 * mu2;
        float sg1 = a11[o] - m11;
        float sg2 = a22[o] - m22;
        float sg12 = a12[o] - m12;
        float num = (2.f * m12 + 1e-4f) * (2.f * sg12 + 9e-4f);
        float den = (m11 + m22 + 1e-4f) * (sg1 + sg2 + 9e-4f);
        lsum += num / den;
    }

    // ---- Block reduction (deterministic): wave shfl + LDS across 8 waves ----
    #pragma unroll
    for (int off = 32; off > 0; off >>= 1) lsum += __shfl_down(lsum, off);
    if ((tid & 63) == 0) wsum[tid >> 6] = lsum;
    __syncthreads();
    if (tid == 0) {
        float bsum = 0.f;
        #pragma unroll
        for (int wv = 0; wv < 8; ++wv) bsum += wsum[wv];
        partials[(blockIdx.z * gridDim.y + blockIdx.y) * gridDim.x + blockIdx.x] = bsum;
    }
}

__global__ void ssim_finalize(const float* __restrict__ partials, float* __restrict__ out)
{
    __shared__ double red[256];
    double s = 0.0;
    for (int i = threadIdx.x; i < NBLOCKS; i += 256) s += (double)partials[i];
    red[threadIdx.x] = s;
    __syncthreads();
    for (int stride = 128; stride > 0; stride >>= 1) {
        if ((int)threadIdx.x < stride) red[threadIdx.x] += red[threadIdx.x + stride];
        __syncthreads();
    }
    if (threadIdx.x == 0) out[0] = (float)(1.0 - red[0] / (double)NPIX);
}

extern "C" void kernel_launch(void* const* d_in, const int* in_sizes, int n_in,
                              void* d_out, int out_size, void* d_ws, size_t ws_size,
                              hipStream_t stream) {
    const float* pred = (const float*)d_in[0];
    const float* targ = (const float*)d_in[1];
    float* out = (float*)d_out;
    float* partials = (float*)d_ws;   // 4096 floats = 16KB, every slot written each call

    Weights wt;
    {
        float g[11];
        float s = 0.f;
        for (int i = 0; i < 11; ++i) {
            float d = (float)(i - 5);
            g[i] = expf(-d * d / (2.f * 1.5f * 1.5f));
            s += g[i];
        }
        for (int i = 0; i < 11; ++i) wt.w[i] = g[i] / s;
    }

    dim3 grid(IMG_W / TILE_X, IMG_H / TILE_Y, 32);   // (8, 16, 32) = 4096 blocks
    ssim_tile_kernel<<<grid, 512, 0, stream>>>(pred, targ, partials, wt);
    ssim_finalize<<<1, 256, 0, stream>>>(partials, out);
}